// Round 12
// baseline (240.194 us; speedup 1.0000x reference)
//
#include <hip/hip_runtime.h>
#include <hip/hip_bf16.h>
#include <stdint.h>

#define DEV_INLINE __device__ __forceinline__

typedef __attribute__((ext_vector_type(4))) float f32x4;
typedef __attribute__((ext_vector_type(16))) float f32x16;
typedef __attribute__((ext_vector_type(8))) short short8;

static constexpr int S_LEN = 2048;
static constexpr int DM = 1024;
static constexpr int NH = 16;
static constexpr int DK = 64;
static constexpr int BATCH = 4;
static constexpr int M_TOT = BATCH * S_LEN;  // 8192

// Q pre-scale: (1/sqrt(64)) * log2(e) so softmax runs in exp2 domain.
#define QSCALE 0.18033688011112042f

DEV_INLINE unsigned short bf_round(float x) {
  unsigned u = __builtin_bit_cast(unsigned, x);
  u += 0x7fffu + ((u >> 16) & 1u);
  return (unsigned short)(u >> 16);
}

// ---------------- fp32 -> bf16 convert, weights only (X handled in-GEMM) ----------------
struct CvtArgs {
  const float* in[4];
  unsigned short* out[4];
};
__global__ __launch_bounds__(256) void cvt_w(CvtArgs a) {
  int bid = blockIdx.x;
  int which = bid >> 9, base = bid & 511;  // 4 weights x 512 blocks
  const float* __restrict__ in = a.in[which];
  unsigned short* __restrict__ out = a.out[which];
  long i = ((long)base * 256 + threadIdx.x) * 8;
  float4 va = *reinterpret_cast<const float4*>(in + i);
  float4 vb = *reinterpret_cast<const float4*>(in + i + 4);
  union { unsigned short u[8]; uint4 v; } pk;
  pk.u[0] = bf_round(va.x); pk.u[1] = bf_round(va.y);
  pk.u[2] = bf_round(va.z); pk.u[3] = bf_round(va.w);
  pk.u[4] = bf_round(vb.x); pk.u[5] = bf_round(vb.y);
  pk.u[6] = bf_round(vb.z); pk.u[7] = bf_round(vb.w);
  *reinterpret_cast<uint4*>(out + i) = pk.v;
}

// ---------------- async global->LDS 16B ----------------
DEV_INLINE void gload_lds16(const unsigned short* g, unsigned short* l) {
  __builtin_amdgcn_global_load_lds(
      (const __attribute__((address_space(1))) unsigned int*)g,
      (__attribute__((address_space(3))) unsigned int*)l,
      16, 0, 0);
}

// ---------------- fused QKV GEMM (A read as fp32, converted during staging) ----------------
struct QkvArgs {
  const unsigned short* W[3];
  const float* bias[3];
  unsigned short* out[3];
};
__global__ __launch_bounds__(256) void gemm_qkv(const float* __restrict__ X,
                                                QkvArgs args) {
  constexpr int K = DM;
  __shared__ unsigned short lA[128 * 32];
  __shared__ unsigned short lB[128 * 32];
  const int tid = threadIdx.x;
  const int wave = tid >> 6, lane = tid & 63;
  const int wm = wave >> 1, wn = wave & 1;
  const int g = lane >> 4, c = lane & 15;
  const int bm = blockIdx.x, bn = blockIdx.y, z = blockIdx.z;

  const unsigned short* __restrict__ W = args.W[z];
  const float* __restrict__ bias = args.bias[z];
  unsigned short* __restrict__ outp = args.out[z];

  const int srow = lane >> 2;       // 0..15
  const int scol = (lane & 3) * 8;  // element col (8-elem group)

  f32x4 acc[4][4] = {};

  const float* Abase = X + (long)(bm * 128) * K;
  const unsigned short* Wbase = W + (long)(bn * 128) * K;

  for (int k0 = 0; k0 < K; k0 += 32) {
    __syncthreads();
#pragma unroll
    for (int i = 0; i < 2; ++i) {
      const int row = i * 64 + wave * 16;
      // A: fp32 load + in-register bf16 convert + ds_write (same LDS bytes as gload)
      const float* src = Abase + (long)(row + srow) * K + k0 + scol;
      float4 a0 = *reinterpret_cast<const float4*>(src);
      float4 a1 = *reinterpret_cast<const float4*>(src + 4);
      union { unsigned short u[8]; uint4 v; } pk;
      pk.u[0] = bf_round(a0.x); pk.u[1] = bf_round(a0.y);
      pk.u[2] = bf_round(a0.z); pk.u[3] = bf_round(a0.w);
      pk.u[4] = bf_round(a1.x); pk.u[5] = bf_round(a1.y);
      pk.u[6] = bf_round(a1.z); pk.u[7] = bf_round(a1.w);
      *reinterpret_cast<uint4*>(&lA[(row + srow) * 32 + scol]) = pk.v;
      // B: async gload as before
      gload_lds16(Wbase + (long)(row + srow) * K + k0 + scol, lB + row * 32);
    }
    __syncthreads();  // drains lgkm (A ds_writes) + vmcnt (B gloads)

    short8 af[4], bf[4];
#pragma unroll
    for (int mi = 0; mi < 4; ++mi)
      af[mi] = *reinterpret_cast<const short8*>(&lA[(wm * 64 + mi * 16 + c) * 32 + g * 8]);
#pragma unroll
    for (int ni = 0; ni < 4; ++ni)
      bf[ni] = *reinterpret_cast<const short8*>(&lB[(wn * 64 + ni * 16 + c) * 32 + g * 8]);
#pragma unroll
    for (int mi = 0; mi < 4; ++mi)
#pragma unroll
      for (int ni = 0; ni < 4; ++ni)
        acc[mi][ni] =
            __builtin_amdgcn_mfma_f32_16x16x32_bf16(af[mi], bf[ni], acc[mi][ni], 0, 0, 0);
  }

#pragma unroll
  for (int mi = 0; mi < 4; ++mi) {
#pragma unroll
    for (int ni = 0; ni < 4; ++ni) {
      const int mg0 = bm * 128 + wm * 64 + mi * 16 + g * 4;
      const int ng = bn * 128 + wn * 64 + ni * 16 + c;
      const float bv = bias[ng];
#pragma unroll
      for (int r = 0; r < 4; ++r) {
        const int m = mg0 + r;
        float v = acc[mi][ni][r] + bv;
        if (z == 0) v *= QSCALE;
        const int b_ = m >> 11, s_ = m & 2047, h_ = ng >> 6, d_ = ng & 63;
        if (z < 2) {
          outp[((long)(b_ * NH + h_) * S_LEN + s_) * DK + d_] = bf_round(v);
        } else {
          outp[((long)(b_ * NH + h_) * DK + d_) * S_LEN + s_] = bf_round(v);
        }
      }
    }
  }
}

// ---------------- output-projection GEMM (fp32 out) ----------------
__global__ __launch_bounds__(256) void gemm_out(const unsigned short* __restrict__ A,
                                                const unsigned short* __restrict__ W,
                                                const float* __restrict__ bias,
                                                float* __restrict__ outp) {
  constexpr int K = DM, N = DM;
  __shared__ unsigned short lA[128 * 32];
  __shared__ unsigned short lB[128 * 32];
  const int tid = threadIdx.x;
  const int wave = tid >> 6, lane = tid & 63;
  const int wm = wave >> 1, wn = wave & 1;
  const int g = lane >> 4, c = lane & 15;
  const int bm = blockIdx.x, bn = blockIdx.y;

  const int srow = lane >> 2;
  const int scol = (lane & 3) * 8;

  f32x4 acc[4][4] = {};

  const unsigned short* Abase = A + (long)(bm * 128) * K;
  const unsigned short* Wbase = W + (long)(bn * 128) * K;

  for (int k0 = 0; k0 < K; k0 += 32) {
    __syncthreads();
#pragma unroll
    for (int i = 0; i < 2; ++i) {
      const int row = i * 64 + wave * 16;
      gload_lds16(Abase + (long)(row + srow) * K + k0 + scol, lA + row * 32);
      gload_lds16(Wbase + (long)(row + srow) * K + k0 + scol, lB + row * 32);
    }
    __syncthreads();

    short8 af[4], bf[4];
#pragma unroll
    for (int mi = 0; mi < 4; ++mi)
      af[mi] = *reinterpret_cast<const short8*>(&lA[(wm * 64 + mi * 16 + c) * 32 + g * 8]);
#pragma unroll
    for (int ni = 0; ni < 4; ++ni)
      bf[ni] = *reinterpret_cast<const short8*>(&lB[(wn * 64 + ni * 16 + c) * 32 + g * 8]);
#pragma unroll
    for (int mi = 0; mi < 4; ++mi)
#pragma unroll
      for (int ni = 0; ni < 4; ++ni)
        acc[mi][ni] =
            __builtin_amdgcn_mfma_f32_16x16x32_bf16(af[mi], bf[ni], acc[mi][ni], 0, 0, 0);
  }

#pragma unroll
  for (int mi = 0; mi < 4; ++mi) {
#pragma unroll
    for (int ni = 0; ni < 4; ++ni) {
      const int mg0 = bm * 128 + wm * 64 + mi * 16 + g * 4;
      const int ng = bn * 128 + wn * 64 + ni * 16 + c;
      const float bv = bias[ng];
#pragma unroll
      for (int r = 0; r < 4; ++r)
        outp[(long)(mg0 + r) * N + ng] = acc[mi][ni][r] + bv;
    }
  }
}

// ---------------- Flash attention: R10-proven structure (4 waves, KV tile 128 = 2x64) ----------------
// Only change vs R10: max-tree restructured into nested triples -> v_max3_f32 (same math).
__global__ __launch_bounds__(256) void attn_kernel(const unsigned short* __restrict__ Q,
                                                   const unsigned short* __restrict__ Kb,
                                                   const unsigned short* __restrict__ Vt,
                                                   unsigned short* __restrict__ ctx) {
  __shared__ unsigned short kbuf[2][2][64 * 64];  // [buf][sub][kv row][d], swizzled
  __shared__ unsigned short vbuf[2][2][64 * 64];  // [buf][sub][d row][kv], swizzled
  const int tid = threadIdx.x, wave = tid >> 6, lane = tid & 63;
  const int q = lane & 31;   // q column; also K/V LDS row selector
  const int h = lane >> 5;   // half-wave: owns k-slice h*8..h*8+7 of frags
  const int bid = blockIdx.x;
  const int swz = (bid & 7) * 128 + (bid >> 3);  // nwg=1024, 8 XCDs, bijective
  const int hd = swz >> 4, qb = swz & 15;
  const int q0 = qb * 128 + wave * 32;

  const unsigned short* Qh = Q + (long)hd * S_LEN * DK;
  const char* KhB = (const char*)(Kb + (long)hd * S_LEN * DK);
  const char* VhB = (const char*)(Vt + (long)hd * DK * S_LEN);

  const int srow_in = lane >> 3;                           // 0..7
  const int scolb = ((lane & 7) * 16) ^ (srow_in << 4);    // swizzled source byte col

  auto ldsrd = [&](const unsigned short* buf, int row, int colbyte) -> short8 {
    return *reinterpret_cast<const short8*>(
        reinterpret_cast<const char*>(buf) + row * 128 + (colbyte ^ ((row & 7) << 4)));
  };

  auto stage = [&](int b, int kv0) {
#pragma unroll
    for (int sub = 0; sub < 2; ++sub) {
#pragma unroll
      for (int r = 0; r < 2; ++r) {
        const int rowbase = (wave * 2 + r) * 8;          // wave-uniform
        const int row = rowbase + srow_in;
        gload_lds16((const unsigned short*)(KhB + (long)(kv0 + sub * 64 + row) * 128 + scolb),
                    &kbuf[b][sub][rowbase * 64]);
        gload_lds16((const unsigned short*)(VhB + (long)row * (S_LEN * 2) +
                                            (kv0 + sub * 64) * 2 + scolb),
                    &vbuf[b][sub][rowbase * 64]);
      }
    }
  };

  short8 qf[4];
#pragma unroll
  for (int d0 = 0; d0 < 4; ++d0)
    qf[d0] = *reinterpret_cast<const short8*>(&Qh[(long)(q0 + q) * DK + d0 * 16 + h * 8]);

  union { short s[8]; short8 v; } ones_u;
#pragma unroll
  for (int i = 0; i < 8; ++i) ones_u.s[i] = (short)0x3F80;
  const short8 ones8 = ones_u.v;

  f32x16 cacc0 = {}, cacc1 = {};  // ctx^T: d-blocks [0..31], [32..63] x 32 q
  f32x16 lacc = {};               // every reg = running sum_kv p̂[kv][q]
  float mrun = -1e30f;

  stage(0, 0);
  __syncthreads();

  int cur = 0;
  for (int t = 0; t < S_LEN / 128; ++t) {
    if (t + 1 < S_LEN / 128) stage(cur ^ 1, (t + 1) * 128);  // issue-early prefetch

#pragma unroll
    for (int p = 0; p < 2; ++p) {
      const unsigned short* kb = kbuf[cur][p];
      const unsigned short* vb = vbuf[cur][p];

      short8 kfA[4], kfB[4];
#pragma unroll
      for (int d0 = 0; d0 < 4; ++d0) {
        kfA[d0] = ldsrd(kb, q, d0 * 32 + h * 16);
        kfB[d0] = ldsrd(kb, 32 + q, d0 * 32 + h * 16);
      }
      __builtin_amdgcn_s_setprio(1);
      f32x16 stA = {}, stB = {};
#pragma unroll
      for (int d0 = 0; d0 < 4; ++d0) {
        stA = __builtin_amdgcn_mfma_f32_32x32x16_bf16(kfA[d0], qf[d0], stA, 0, 0, 0);
        stB = __builtin_amdgcn_mfma_f32_32x32x16_bf16(kfB[d0], qf[d0], stB, 0, 0, 0);
      }
      __builtin_amdgcn_s_setprio(0);

      // ---- max reduction via nested triples (v_max3) ----
      float m0 = fmaxf(fmaxf(stA[0], stA[1]), stA[2]);
      float m1 = fmaxf(fmaxf(stA[3], stA[4]), stA[5]);
      float m2 = fmaxf(fmaxf(stA[6], stA[7]), stA[8]);
      float m3 = fmaxf(fmaxf(stA[9], stA[10]), stA[11]);
      float m4 = fmaxf(fmaxf(stA[12], stA[13]), stA[14]);
      float m5 = fmaxf(fmaxf(stA[15], stB[0]), stB[1]);
      float m6 = fmaxf(fmaxf(stB[2], stB[3]), stB[4]);
      float m7 = fmaxf(fmaxf(stB[5], stB[6]), stB[7]);
      float m8 = fmaxf(fmaxf(stB[8], stB[9]), stB[10]);
      float m9 = fmaxf(fmaxf(stB[11], stB[12]), stB[13]);
      float n0 = fmaxf(fmaxf(m0, m1), m2);
      float n1 = fmaxf(fmaxf(m3, m4), m5);
      float n2 = fmaxf(fmaxf(m6, m7), m8);
      float n3 = fmaxf(fmaxf(m9, stB[14]), stB[15]);
      const float pml = fmaxf(fmaxf(n0, n1), fmaxf(n2, n3));

      if (__any(pml > mrun + 8.0f)) {  // rare; shfl only inside the branch
        const float pm = fmaxf(pml, __shfl_xor(pml, 32));
        const float mnew = fmaxf(mrun, pm);
        const float alpha = __builtin_amdgcn_exp2f(mrun - mnew);
        cacc0 *= alpha;
        cacc1 *= alpha;
        lacc *= alpha;
        mrun = mnew;  // stays pair-uniform: pm is pair-reduced
      }

#pragma unroll
      for (int r = 0; r < 16; ++r) {
        stA[r] = __builtin_amdgcn_exp2f(stA[r] - mrun);
        stB[r] = __builtin_amdgcn_exp2f(stB[r] - mrun);
      }

      unsigned pAA[4], pAB[4], pBA[4], pBB[4];
#pragma unroll
      for (int rq = 0; rq < 4; ++rq) {
        asm("v_cvt_pk_bf16_f32 %0, %1, %2" : "=v"(pAA[rq]) : "v"(stA[4 * rq]), "v"(stA[4 * rq + 1]));
        asm("v_cvt_pk_bf16_f32 %0, %1, %2" : "=v"(pAB[rq]) : "v"(stA[4 * rq + 2]), "v"(stA[4 * rq + 3]));
        asm("v_cvt_pk_bf16_f32 %0, %1, %2" : "=v"(pBA[rq]) : "v"(stB[4 * rq]), "v"(stB[4 * rq + 1]));
        asm("v_cvt_pk_bf16_f32 %0, %1, %2" : "=v"(pBB[rq]) : "v"(stB[4 * rq + 2]), "v"(stB[4 * rq + 3]));
      }

      unsigned rA[4], rB[4];
#pragma unroll
      for (int s = 0; s < 4; ++s) {
        const unsigned a0 = (s < 2 ? pAA : pBA)[2 * (s & 1)];
        const unsigned a1 = (s < 2 ? pAA : pBA)[2 * (s & 1) + 1];
        const unsigned b0 = (s < 2 ? pAB : pBB)[2 * (s & 1)];
        const unsigned b1 = (s < 2 ? pAB : pBB)[2 * (s & 1) + 1];
        rA[s] = (unsigned)__shfl_xor((int)(h ? a0 : a1), 32);
        rB[s] = (unsigned)__shfl_xor((int)(h ? b0 : b1), 32);
      }
      short8 vf0[4], vf1[4];
#pragma unroll
      for (int s = 0; s < 4; ++s) {
        vf0[s] = ldsrd(vb, q, s * 32 + h * 16);
        vf1[s] = ldsrd(vb, 32 + q, s * 32 + h * 16);
      }
      __builtin_amdgcn_s_setprio(1);
#pragma unroll
      for (int s = 0; s < 4; ++s) {
        const unsigned a0 = (s < 2 ? pAA : pBA)[2 * (s & 1)];
        const unsigned a1 = (s < 2 ? pAA : pBA)[2 * (s & 1) + 1];
        const unsigned b0 = (s < 2 ? pAB : pBB)[2 * (s & 1)];
        const unsigned b1 = (s < 2 ? pAB : pBB)[2 * (s & 1) + 1];
        union { unsigned w[4]; short8 v; } pf;
        pf.w[0] = h ? rA[s] : a0;
        pf.w[1] = h ? rB[s] : b0;
        pf.w[2] = h ? a1 : rA[s];
        pf.w[3] = h ? b1 : rB[s];
        cacc0 = __builtin_amdgcn_mfma_f32_32x32x16_bf16(vf0[s], pf.v, cacc0, 0, 0, 0);
        cacc1 = __builtin_amdgcn_mfma_f32_32x32x16_bf16(vf1[s], pf.v, cacc1, 0, 0, 0);
        lacc = __builtin_amdgcn_mfma_f32_32x32x16_bf16(ones8, pf.v, lacc, 0, 0, 0);
      }
      __builtin_amdgcn_s_setprio(0);
    }

    __syncthreads();  // drains stage loads; protects both buffers
    cur ^= 1;
  }

  // ---- epilogue: l from ones-MFMA (all regs equal, both halves equal) ----
  const float inv = 1.0f / lacc[0];
  const int b_ = hd >> 4, h_ = hd & 15;
  const long row = ((long)b_ * S_LEN + q0 + q) * DM + h_ * DK;
#pragma unroll
  for (int rq = 0; rq < 4; ++rq) {
    ushort4 w0, w1;
    w0.x = bf_round(cacc0[4 * rq + 0] * inv);
    w0.y = bf_round(cacc0[4 * rq + 1] * inv);
    w0.z = bf_round(cacc0[4 * rq + 2] * inv);
    w0.w = bf_round(cacc0[4 * rq + 3] * inv);
    w1.x = bf_round(cacc1[4 * rq + 0] * inv);
    w1.y = bf_round(cacc1[4 * rq + 1] * inv);
    w1.z = bf_round(cacc1[4 * rq + 2] * inv);
    w1.w = bf_round(cacc1[4 * rq + 3] * inv);
    *reinterpret_cast<ushort4*>(&ctx[row + 8 * rq + 4 * h]) = w0;
    *reinterpret_cast<ushort4*>(&ctx[row + 32 + 8 * rq + 4 * h]) = w1;
  }
}

extern "C" void kernel_launch(void* const* d_in, const int* in_sizes, int n_in,
                              void* d_out, int out_size, void* d_ws, size_t ws_size,
                              hipStream_t stream) {
  const float* X  = (const float*)d_in[0];
  const float* Wq = (const float*)d_in[1];
  const float* bq = (const float*)d_in[2];
  const float* Wk = (const float*)d_in[3];
  const float* bk = (const float*)d_in[4];
  const float* Wv = (const float*)d_in[5];
  const float* bv = (const float*)d_in[6];
  const float* Wo = (const float*)d_in[7];
  const float* bo = (const float*)d_in[8];

  char* ws = (char*)d_ws;
  const long MB = 1l << 20;
  unsigned short* Ctx = (unsigned short*)(ws + 0 * MB);   // 16 MB (X no longer staged)
  unsigned short* Wqb = (unsigned short*)(ws + 16 * MB);  // 2 MB each
  unsigned short* Wkb = (unsigned short*)(ws + 18 * MB);
  unsigned short* Wvb = (unsigned short*)(ws + 20 * MB);
  unsigned short* Wob = (unsigned short*)(ws + 22 * MB);
  unsigned short* Qb  = (unsigned short*)(ws + 24 * MB);  // 16 MB
  unsigned short* Kbf = (unsigned short*)(ws + 40 * MB);  // 16 MB
  unsigned short* Vtb = (unsigned short*)(ws + 56 * MB);  // 16 MB, ends at 72 MB

  CvtArgs ca;
  ca.in[0] = Wq; ca.out[0] = Wqb;
  ca.in[1] = Wk; ca.out[1] = Wkb;
  ca.in[2] = Wv; ca.out[2] = Wvb;
  ca.in[3] = Wo; ca.out[3] = Wob;
  cvt_w<<<4 * 512, 256, 0, stream>>>(ca);

  QkvArgs qa;
  qa.W[0] = Wqb; qa.bias[0] = bq; qa.out[0] = Qb;
  qa.W[1] = Wkb; qa.bias[1] = bk; qa.out[1] = Kbf;
  qa.W[2] = Wvb; qa.bias[2] = bv; qa.out[2] = Vtb;
  gemm_qkv<<<dim3(M_TOT / 128, DM / 128, 3), 256, 0, stream>>>(X, qa);

  attn_kernel<<<dim3(1024), 256, 0, stream>>>(Qb, Kbf, Vtb, Ctx);

  gemm_out<<<dim3(M_TOT / 128, DM / 128), 256, 0, stream>>>(Ctx, Wob, bo, (float*)d_out);
}

// Round 13
// 223.611 us; speedup vs baseline: 1.0742x; 1.0742x over previous
//
#include <hip/hip_runtime.h>
#include <hip/hip_bf16.h>
#include <stdint.h>

#define DEV_INLINE __device__ __forceinline__

typedef __attribute__((ext_vector_type(4))) float f32x4;
typedef __attribute__((ext_vector_type(16))) float f32x16;
typedef __attribute__((ext_vector_type(8))) short short8;

static constexpr int S_LEN = 2048;
static constexpr int DM = 1024;
static constexpr int NH = 16;
static constexpr int DK = 64;
static constexpr int BATCH = 4;
static constexpr int M_TOT = BATCH * S_LEN;  // 8192

// Q pre-scale: (1/sqrt(64)) * log2(e) so softmax runs in exp2 domain.
#define QSCALE 0.18033688011112042f

DEV_INLINE unsigned short bf_round(float x) {
  unsigned u = __builtin_bit_cast(unsigned, x);
  u += 0x7fffu + ((u >> 16) & 1u);
  return (unsigned short)(u >> 16);
}

// ---------------- fp32 -> bf16 convert, all 5 tensors in one dispatch ----------------
struct CvtArgs {
  const float* in[5];
  unsigned short* out[5];
};
__global__ __launch_bounds__(256) void cvt_all(CvtArgs a) {
  int bid = blockIdx.x;
  int which, base;
  if (bid < 4096) { which = 0; base = bid; }
  else { int r = bid - 4096; which = 1 + (r >> 9); base = r & 511; }
  const float* __restrict__ in = a.in[which];
  unsigned short* __restrict__ out = a.out[which];
  long i = ((long)base * 256 + threadIdx.x) * 8;
  float4 va = *reinterpret_cast<const float4*>(in + i);
  float4 vb = *reinterpret_cast<const float4*>(in + i + 4);
  union { unsigned short u[8]; uint4 v; } pk;
  pk.u[0] = bf_round(va.x); pk.u[1] = bf_round(va.y);
  pk.u[2] = bf_round(va.z); pk.u[3] = bf_round(va.w);
  pk.u[4] = bf_round(vb.x); pk.u[5] = bf_round(vb.y);
  pk.u[6] = bf_round(vb.z); pk.u[7] = bf_round(vb.w);
  *reinterpret_cast<uint4*>(out + i) = pk.v;
}

// ---------------- async global->LDS 16B ----------------
DEV_INLINE void gload_lds16(const unsigned short* g, unsigned short* l) {
  __builtin_amdgcn_global_load_lds(
      (const __attribute__((address_space(1))) unsigned int*)g,
      (__attribute__((address_space(3))) unsigned int*)l,
      16, 0, 0);
}

// ---------------- fused QKV GEMM (bf16 A via global_load_lds — R10-proven) ----------------
struct QkvArgs {
  const unsigned short* W[3];
  const float* bias[3];
  unsigned short* out[3];
};
__global__ __launch_bounds__(256) void gemm_qkv(const unsigned short* __restrict__ A,
                                                QkvArgs args) {
  constexpr int K = DM;
  __shared__ unsigned short lA[128 * 32];
  __shared__ unsigned short lB[128 * 32];
  const int tid = threadIdx.x;
  const int wave = tid >> 6, lane = tid & 63;
  const int wm = wave >> 1, wn = wave & 1;
  const int g = lane >> 4, c = lane & 15;
  const int bm = blockIdx.x, bn = blockIdx.y, z = blockIdx.z;

  const unsigned short* __restrict__ W = args.W[z];
  const float* __restrict__ bias = args.bias[z];
  unsigned short* __restrict__ outp = args.out[z];

  const int srow = lane >> 2;
  const int scol = (lane & 3) * 8;

  f32x4 acc[4][4] = {};

  const unsigned short* Abase = A + (long)(bm * 128) * K;
  const unsigned short* Wbase = W + (long)(bn * 128) * K;

  for (int k0 = 0; k0 < K; k0 += 32) {
    __syncthreads();
#pragma unroll
    for (int i = 0; i < 2; ++i) {
      const int row = i * 64 + wave * 16;
      gload_lds16(Abase + (long)(row + srow) * K + k0 + scol, lA + row * 32);
      gload_lds16(Wbase + (long)(row + srow) * K + k0 + scol, lB + row * 32);
    }
    __syncthreads();

    short8 af[4], bf[4];
#pragma unroll
    for (int mi = 0; mi < 4; ++mi)
      af[mi] = *reinterpret_cast<const short8*>(&lA[(wm * 64 + mi * 16 + c) * 32 + g * 8]);
#pragma unroll
    for (int ni = 0; ni < 4; ++ni)
      bf[ni] = *reinterpret_cast<const short8*>(&lB[(wn * 64 + ni * 16 + c) * 32 + g * 8]);
#pragma unroll
    for (int mi = 0; mi < 4; ++mi)
#pragma unroll
      for (int ni = 0; ni < 4; ++ni)
        acc[mi][ni] =
            __builtin_amdgcn_mfma_f32_16x16x32_bf16(af[mi], bf[ni], acc[mi][ni], 0, 0, 0);
  }

#pragma unroll
  for (int mi = 0; mi < 4; ++mi) {
#pragma unroll
    for (int ni = 0; ni < 4; ++ni) {
      const int mg0 = bm * 128 + wm * 64 + mi * 16 + g * 4;
      const int ng = bn * 128 + wn * 64 + ni * 16 + c;
      const float bv = bias[ng];
#pragma unroll
      for (int r = 0; r < 4; ++r) {
        const int m = mg0 + r;
        float v = acc[mi][ni][r] + bv;
        if (z == 0) v *= QSCALE;
        const int b_ = m >> 11, s_ = m & 2047, h_ = ng >> 6, d_ = ng & 63;
        if (z < 2) {
          outp[((long)(b_ * NH + h_) * S_LEN + s_) * DK + d_] = bf_round(v);
        } else {
          outp[((long)(b_ * NH + h_) * DK + d_) * S_LEN + s_] = bf_round(v);
        }
      }
    }
  }
}

// ---------------- output-projection GEMM (fp32 out) ----------------
__global__ __launch_bounds__(256) void gemm_out(const unsigned short* __restrict__ A,
                                                const unsigned short* __restrict__ W,
                                                const float* __restrict__ bias,
                                                float* __restrict__ outp) {
  constexpr int K = DM, N = DM;
  __shared__ unsigned short lA[128 * 32];
  __shared__ unsigned short lB[128 * 32];
  const int tid = threadIdx.x;
  const int wave = tid >> 6, lane = tid & 63;
  const int wm = wave >> 1, wn = wave & 1;
  const int g = lane >> 4, c = lane & 15;
  const int bm = blockIdx.x, bn = blockIdx.y;

  const int srow = lane >> 2;
  const int scol = (lane & 3) * 8;

  f32x4 acc[4][4] = {};

  const unsigned short* Abase = A + (long)(bm * 128) * K;
  const unsigned short* Wbase = W + (long)(bn * 128) * K;

  for (int k0 = 0; k0 < K; k0 += 32) {
    __syncthreads();
#pragma unroll
    for (int i = 0; i < 2; ++i) {
      const int row = i * 64 + wave * 16;
      gload_lds16(Abase + (long)(row + srow) * K + k0 + scol, lA + row * 32);
      gload_lds16(Wbase + (long)(row + srow) * K + k0 + scol, lB + row * 32);
    }
    __syncthreads();

    short8 af[4], bf[4];
#pragma unroll
    for (int mi = 0; mi < 4; ++mi)
      af[mi] = *reinterpret_cast<const short8*>(&lA[(wm * 64 + mi * 16 + c) * 32 + g * 8]);
#pragma unroll
    for (int ni = 0; ni < 4; ++ni)
      bf[ni] = *reinterpret_cast<const short8*>(&lB[(wn * 64 + ni * 16 + c) * 32 + g * 8]);
#pragma unroll
    for (int mi = 0; mi < 4; ++mi)
#pragma unroll
      for (int ni = 0; ni < 4; ++ni)
        acc[mi][ni] =
            __builtin_amdgcn_mfma_f32_16x16x32_bf16(af[mi], bf[ni], acc[mi][ni], 0, 0, 0);
  }

#pragma unroll
  for (int mi = 0; mi < 4; ++mi) {
#pragma unroll
    for (int ni = 0; ni < 4; ++ni) {
      const int mg0 = bm * 128 + wm * 64 + mi * 16 + g * 4;
      const int ng = bn * 128 + wn * 64 + ni * 16 + c;
      const float bv = bias[ng];
#pragma unroll
      for (int r = 0; r < 4; ++r)
        outp[(long)(mg0 + r) * N + ng] = acc[mi][ni][r] + bv;
    }
  }
}

// ---------------- Flash attention: R10 structure + max3 tree (both proven) ----------------
__global__ __launch_bounds__(256) void attn_kernel(const unsigned short* __restrict__ Q,
                                                   const unsigned short* __restrict__ Kb,
                                                   const unsigned short* __restrict__ Vt,
                                                   unsigned short* __restrict__ ctx) {
  __shared__ unsigned short kbuf[2][2][64 * 64];  // [buf][sub][kv row][d], swizzled
  __shared__ unsigned short vbuf[2][2][64 * 64];  // [buf][sub][d row][kv], swizzled
  const int tid = threadIdx.x, wave = tid >> 6, lane = tid & 63;
  const int q = lane & 31;   // q column; also K/V LDS row selector
  const int h = lane >> 5;   // half-wave: owns k-slice h*8..h*8+7 of frags
  const int bid = blockIdx.x;
  const int swz = (bid & 7) * 128 + (bid >> 3);  // nwg=1024, 8 XCDs, bijective
  const int hd = swz >> 4, qb = swz & 15;
  const int q0 = qb * 128 + wave * 32;

  const unsigned short* Qh = Q + (long)hd * S_LEN * DK;
  const char* KhB = (const char*)(Kb + (long)hd * S_LEN * DK);
  const char* VhB = (const char*)(Vt + (long)hd * DK * S_LEN);

  const int srow_in = lane >> 3;                           // 0..7
  const int scolb = ((lane & 7) * 16) ^ (srow_in << 4);    // swizzled source byte col

  auto ldsrd = [&](const unsigned short* buf, int row, int colbyte) -> short8 {
    return *reinterpret_cast<const short8*>(
        reinterpret_cast<const char*>(buf) + row * 128 + (colbyte ^ ((row & 7) << 4)));
  };

  auto stage = [&](int b, int kv0) {
#pragma unroll
    for (int sub = 0; sub < 2; ++sub) {
#pragma unroll
      for (int r = 0; r < 2; ++r) {
        const int rowbase = (wave * 2 + r) * 8;          // wave-uniform
        const int row = rowbase + srow_in;
        gload_lds16((const unsigned short*)(KhB + (long)(kv0 + sub * 64 + row) * 128 + scolb),
                    &kbuf[b][sub][rowbase * 64]);
        gload_lds16((const unsigned short*)(VhB + (long)row * (S_LEN * 2) +
                                            (kv0 + sub * 64) * 2 + scolb),
                    &vbuf[b][sub][rowbase * 64]);
      }
    }
  };

  short8 qf[4];
#pragma unroll
  for (int d0 = 0; d0 < 4; ++d0)
    qf[d0] = *reinterpret_cast<const short8*>(&Qh[(long)(q0 + q) * DK + d0 * 16 + h * 8]);

  union { short s[8]; short8 v; } ones_u;
#pragma unroll
  for (int i = 0; i < 8; ++i) ones_u.s[i] = (short)0x3F80;
  const short8 ones8 = ones_u.v;

  f32x16 cacc0 = {}, cacc1 = {};  // ctx^T: d-blocks [0..31], [32..63] x 32 q
  f32x16 lacc = {};               // every reg = running sum_kv p̂[kv][q]
  float mrun = -1e30f;

  stage(0, 0);
  __syncthreads();

  int cur = 0;
  for (int t = 0; t < S_LEN / 128; ++t) {
    if (t + 1 < S_LEN / 128) stage(cur ^ 1, (t + 1) * 128);  // issue-early prefetch

#pragma unroll
    for (int p = 0; p < 2; ++p) {
      const unsigned short* kb = kbuf[cur][p];
      const unsigned short* vb = vbuf[cur][p];

      short8 kfA[4], kfB[4];
#pragma unroll
      for (int d0 = 0; d0 < 4; ++d0) {
        kfA[d0] = ldsrd(kb, q, d0 * 32 + h * 16);
        kfB[d0] = ldsrd(kb, 32 + q, d0 * 32 + h * 16);
      }
      __builtin_amdgcn_s_setprio(1);
      f32x16 stA = {}, stB = {};
#pragma unroll
      for (int d0 = 0; d0 < 4; ++d0) {
        stA = __builtin_amdgcn_mfma_f32_32x32x16_bf16(kfA[d0], qf[d0], stA, 0, 0, 0);
        stB = __builtin_amdgcn_mfma_f32_32x32x16_bf16(kfB[d0], qf[d0], stB, 0, 0, 0);
      }
      __builtin_amdgcn_s_setprio(0);

      // ---- max reduction via nested triples (v_max3) ----
      float m0 = fmaxf(fmaxf(stA[0], stA[1]), stA[2]);
      float m1 = fmaxf(fmaxf(stA[3], stA[4]), stA[5]);
      float m2 = fmaxf(fmaxf(stA[6], stA[7]), stA[8]);
      float m3 = fmaxf(fmaxf(stA[9], stA[10]), stA[11]);
      float m4 = fmaxf(fmaxf(stA[12], stA[13]), stA[14]);
      float m5 = fmaxf(fmaxf(stA[15], stB[0]), stB[1]);
      float m6 = fmaxf(fmaxf(stB[2], stB[3]), stB[4]);
      float m7 = fmaxf(fmaxf(stB[5], stB[6]), stB[7]);
      float m8 = fmaxf(fmaxf(stB[8], stB[9]), stB[10]);
      float m9 = fmaxf(fmaxf(stB[11], stB[12]), stB[13]);
      float n0 = fmaxf(fmaxf(m0, m1), m2);
      float n1 = fmaxf(fmaxf(m3, m4), m5);
      float n2 = fmaxf(fmaxf(m6, m7), m8);
      float n3 = fmaxf(fmaxf(m9, stB[14]), stB[15]);
      const float pml = fmaxf(fmaxf(n0, n1), fmaxf(n2, n3));

      if (__any(pml > mrun + 8.0f)) {  // rare; shfl only inside the branch
        const float pm = fmaxf(pml, __shfl_xor(pml, 32));
        const float mnew = fmaxf(mrun, pm);
        const float alpha = __builtin_amdgcn_exp2f(mrun - mnew);
        cacc0 *= alpha;
        cacc1 *= alpha;
        lacc *= alpha;
        mrun = mnew;  // stays pair-uniform: pm is pair-reduced
      }

#pragma unroll
      for (int r = 0; r < 16; ++r) {
        stA[r] = __builtin_amdgcn_exp2f(stA[r] - mrun);
        stB[r] = __builtin_amdgcn_exp2f(stB[r] - mrun);
      }

      unsigned pAA[4], pAB[4], pBA[4], pBB[4];
#pragma unroll
      for (int rq = 0; rq < 4; ++rq) {
        asm("v_cvt_pk_bf16_f32 %0, %1, %2" : "=v"(pAA[rq]) : "v"(stA[4 * rq]), "v"(stA[4 * rq + 1]));
        asm("v_cvt_pk_bf16_f32 %0, %1, %2" : "=v"(pAB[rq]) : "v"(stA[4 * rq + 2]), "v"(stA[4 * rq + 3]));
        asm("v_cvt_pk_bf16_f32 %0, %1, %2" : "=v"(pBA[rq]) : "v"(stB[4 * rq]), "v"(stB[4 * rq + 1]));
        asm("v_cvt_pk_bf16_f32 %0, %1, %2" : "=v"(pBB[rq]) : "v"(stB[4 * rq + 2]), "v"(stB[4 * rq + 3]));
      }

      unsigned rA[4], rB[4];
#pragma unroll
      for (int s = 0; s < 4; ++s) {
        const unsigned a0 = (s < 2 ? pAA : pBA)[2 * (s & 1)];
        const unsigned a1 = (s < 2 ? pAA : pBA)[2 * (s & 1) + 1];
        const unsigned b0 = (s < 2 ? pAB : pBB)[2 * (s & 1)];
        const unsigned b1 = (s < 2 ? pAB : pBB)[2 * (s & 1) + 1];
        rA[s] = (unsigned)__shfl_xor((int)(h ? a0 : a1), 32);
        rB[s] = (unsigned)__shfl_xor((int)(h ? b0 : b1), 32);
      }
      short8 vf0[4], vf1[4];
#pragma unroll
      for (int s = 0; s < 4; ++s) {
        vf0[s] = ldsrd(vb, q, s * 32 + h * 16);
        vf1[s] = ldsrd(vb, 32 + q, s * 32 + h * 16);
      }
      __builtin_amdgcn_s_setprio(1);
#pragma unroll
      for (int s = 0; s < 4; ++s) {
        const unsigned a0 = (s < 2 ? pAA : pBA)[2 * (s & 1)];
        const unsigned a1 = (s < 2 ? pAA : pBA)[2 * (s & 1) + 1];
        const unsigned b0 = (s < 2 ? pAB : pBB)[2 * (s & 1)];
        const unsigned b1 = (s < 2 ? pAB : pBB)[2 * (s & 1) + 1];
        union { unsigned w[4]; short8 v; } pf;
        pf.w[0] = h ? rA[s] : a0;
        pf.w[1] = h ? rB[s] : b0;
        pf.w[2] = h ? a1 : rA[s];
        pf.w[3] = h ? b1 : rB[s];
        cacc0 = __builtin_amdgcn_mfma_f32_32x32x16_bf16(vf0[s], pf.v, cacc0, 0, 0, 0);
        cacc1 = __builtin_amdgcn_mfma_f32_32x32x16_bf16(vf1[s], pf.v, cacc1, 0, 0, 0);
        lacc = __builtin_amdgcn_mfma_f32_32x32x16_bf16(ones8, pf.v, lacc, 0, 0, 0);
      }
      __builtin_amdgcn_s_setprio(0);
    }

    __syncthreads();  // drains stage loads; protects both buffers
    cur ^= 1;
  }

  // ---- epilogue: l from ones-MFMA (all regs equal, both halves equal) ----
  const float inv = 1.0f / lacc[0];
  const int b_ = hd >> 4, h_ = hd & 15;
  const long row = ((long)b_ * S_LEN + q0 + q) * DM + h_ * DK;
#pragma unroll
  for (int rq = 0; rq < 4; ++rq) {
    ushort4 w0, w1;
    w0.x = bf_round(cacc0[4 * rq + 0] * inv);
    w0.y = bf_round(cacc0[4 * rq + 1] * inv);
    w0.z = bf_round(cacc0[4 * rq + 2] * inv);
    w0.w = bf_round(cacc0[4 * rq + 3] * inv);
    w1.x = bf_round(cacc1[4 * rq + 0] * inv);
    w1.y = bf_round(cacc1[4 * rq + 1] * inv);
    w1.z = bf_round(cacc1[4 * rq + 2] * inv);
    w1.w = bf_round(cacc1[4 * rq + 3] * inv);
    *reinterpret_cast<ushort4*>(&ctx[row + 8 * rq + 4 * h]) = w0;
    *reinterpret_cast<ushort4*>(&ctx[row + 32 + 8 * rq + 4 * h]) = w1;
  }
}

extern "C" void kernel_launch(void* const* d_in, const int* in_sizes, int n_in,
                              void* d_out, int out_size, void* d_ws, size_t ws_size,
                              hipStream_t stream) {
  const float* X  = (const float*)d_in[0];
  const float* Wq = (const float*)d_in[1];
  const float* bq = (const float*)d_in[2];
  const float* Wk = (const float*)d_in[3];
  const float* bk = (const float*)d_in[4];
  const float* Wv = (const float*)d_in[5];
  const float* bv = (const float*)d_in[6];
  const float* Wo = (const float*)d_in[7];
  const float* bo = (const float*)d_in[8];

  char* ws = (char*)d_ws;
  const long MB = 1l << 20;
  unsigned short* Xbf = (unsigned short*)(ws + 0 * MB);   // 16 MB
  unsigned short* Ctx = Xbf;                              // alias: X dead after V GEMM
  unsigned short* Wqb = (unsigned short*)(ws + 16 * MB);  // 2 MB each
  unsigned short* Wkb = (unsigned short*)(ws + 18 * MB);
  unsigned short* Wvb = (unsigned short*)(ws + 20 * MB);
  unsigned short* Wob = (unsigned short*)(ws + 22 * MB);
  unsigned short* Qb  = (unsigned short*)(ws + 24 * MB);  // 16 MB
  unsigned short* Kbf = (unsigned short*)(ws + 40 * MB);  // 16 MB
  unsigned short* Vtb = (unsigned short*)(ws + 56 * MB);  // 16 MB, ends at 72 MB

  CvtArgs ca;
  ca.in[0] = X;  ca.out[0] = Xbf;
  ca.in[1] = Wq; ca.out[1] = Wqb;
  ca.in[2] = Wk; ca.out[2] = Wkb;
  ca.in[3] = Wv; ca.out[3] = Wvb;
  ca.in[4] = Wo; ca.out[4] = Wob;
  cvt_all<<<4096 + 4 * 512, 256, 0, stream>>>(ca);

  QkvArgs qa;
  qa.W[0] = Wqb; qa.bias[0] = bq; qa.out[0] = Qb;
  qa.W[1] = Wkb; qa.bias[1] = bk; qa.out[1] = Kbf;
  qa.W[2] = Wvb; qa.bias[2] = bv; qa.out[2] = Vtb;
  gemm_qkv<<<dim3(M_TOT / 128, DM / 128, 3), 256, 0, stream>>>(Xbf, qa);

  attn_kernel<<<dim3(1024), 256, 0, stream>>>(Qb, Kbf, Vtb, Ctx);

  gemm_out<<<dim3(M_TOT / 128, DM / 128), 256, 0, stream>>>(Ctx, Wob, bo, (float*)d_out);
}

// Round 14
// 215.883 us; speedup vs baseline: 1.1126x; 1.0358x over previous
//
#include <hip/hip_runtime.h>
#include <hip/hip_bf16.h>
#include <stdint.h>

#define DEV_INLINE __device__ __forceinline__

typedef __attribute__((ext_vector_type(4))) float f32x4;
typedef __attribute__((ext_vector_type(16))) float f32x16;
typedef __attribute__((ext_vector_type(8))) short short8;
typedef __attribute__((ext_vector_type(2))) unsigned uint2v;

static constexpr int S_LEN = 2048;
static constexpr int DM = 1024;
static constexpr int NH = 16;
static constexpr int DK = 64;
static constexpr int BATCH = 4;
static constexpr int M_TOT = BATCH * S_LEN;  // 8192

// Q pre-scale: (1/sqrt(64)) * log2(e) so softmax runs in exp2 domain.
#define QSCALE 0.18033688011112042f

DEV_INLINE unsigned short bf_round(float x) {
  unsigned u = __builtin_bit_cast(unsigned, x);
  u += 0x7fffu + ((u >> 16) & 1u);
  return (unsigned short)(u >> 16);
}

// ---------------- fp32 -> bf16 convert, all 5 tensors in one dispatch ----------------
struct CvtArgs {
  const float* in[5];
  unsigned short* out[5];
};
__global__ __launch_bounds__(256) void cvt_all(CvtArgs a) {
  int bid = blockIdx.x;
  int which, base;
  if (bid < 4096) { which = 0; base = bid; }
  else { int r = bid - 4096; which = 1 + (r >> 9); base = r & 511; }
  const float* __restrict__ in = a.in[which];
  unsigned short* __restrict__ out = a.out[which];
  long i = ((long)base * 256 + threadIdx.x) * 8;
  float4 va = *reinterpret_cast<const float4*>(in + i);
  float4 vb = *reinterpret_cast<const float4*>(in + i + 4);
  union { unsigned short u[8]; uint4 v; } pk;
  pk.u[0] = bf_round(va.x); pk.u[1] = bf_round(va.y);
  pk.u[2] = bf_round(va.z); pk.u[3] = bf_round(va.w);
  pk.u[4] = bf_round(vb.x); pk.u[5] = bf_round(vb.y);
  pk.u[6] = bf_round(vb.z); pk.u[7] = bf_round(vb.w);
  *reinterpret_cast<uint4*>(out + i) = pk.v;
}

// ---------------- async global->LDS 16B ----------------
DEV_INLINE void gload_lds16(const unsigned short* g, unsigned short* l) {
  __builtin_amdgcn_global_load_lds(
      (const __attribute__((address_space(1))) unsigned int*)g,
      (__attribute__((address_space(3))) unsigned int*)l,
      16, 0, 0);
}

// ---------------- fused QKV GEMM (bf16 A via global_load_lds — R10-proven) ----------------
struct QkvArgs {
  const unsigned short* W[3];
  const float* bias[3];
  unsigned short* out[3];
};
__global__ __launch_bounds__(256) void gemm_qkv(const unsigned short* __restrict__ A,
                                                QkvArgs args) {
  constexpr int K = DM;
  __shared__ unsigned short lA[128 * 32];
  __shared__ unsigned short lB[128 * 32];
  const int tid = threadIdx.x;
  const int wave = tid >> 6, lane = tid & 63;
  const int wm = wave >> 1, wn = wave & 1;
  const int g = lane >> 4, c = lane & 15;
  const int bm = blockIdx.x, bn = blockIdx.y, z = blockIdx.z;

  const unsigned short* __restrict__ W = args.W[z];
  const float* __restrict__ bias = args.bias[z];
  unsigned short* __restrict__ outp = args.out[z];

  const int srow = lane >> 2;
  const int scol = (lane & 3) * 8;

  f32x4 acc[4][4] = {};

  const unsigned short* Abase = A + (long)(bm * 128) * K;
  const unsigned short* Wbase = W + (long)(bn * 128) * K;

  for (int k0 = 0; k0 < K; k0 += 32) {
    __syncthreads();
#pragma unroll
    for (int i = 0; i < 2; ++i) {
      const int row = i * 64 + wave * 16;
      gload_lds16(Abase + (long)(row + srow) * K + k0 + scol, lA + row * 32);
      gload_lds16(Wbase + (long)(row + srow) * K + k0 + scol, lB + row * 32);
    }
    __syncthreads();

    short8 af[4], bf[4];
#pragma unroll
    for (int mi = 0; mi < 4; ++mi)
      af[mi] = *reinterpret_cast<const short8*>(&lA[(wm * 64 + mi * 16 + c) * 32 + g * 8]);
#pragma unroll
    for (int ni = 0; ni < 4; ++ni)
      bf[ni] = *reinterpret_cast<const short8*>(&lB[(wn * 64 + ni * 16 + c) * 32 + g * 8]);
#pragma unroll
    for (int mi = 0; mi < 4; ++mi)
#pragma unroll
      for (int ni = 0; ni < 4; ++ni)
        acc[mi][ni] =
            __builtin_amdgcn_mfma_f32_16x16x32_bf16(af[mi], bf[ni], acc[mi][ni], 0, 0, 0);
  }

#pragma unroll
  for (int mi = 0; mi < 4; ++mi) {
#pragma unroll
    for (int ni = 0; ni < 4; ++ni) {
      const int mg0 = bm * 128 + wm * 64 + mi * 16 + g * 4;
      const int ng = bn * 128 + wn * 64 + ni * 16 + c;
      const float bv = bias[ng];
#pragma unroll
      for (int r = 0; r < 4; ++r) {
        const int m = mg0 + r;
        float v = acc[mi][ni][r] + bv;
        if (z == 0) v *= QSCALE;
        const int b_ = m >> 11, s_ = m & 2047, h_ = ng >> 6, d_ = ng & 63;
        if (z < 2) {
          outp[((long)(b_ * NH + h_) * S_LEN + s_) * DK + d_] = bf_round(v);
        } else {
          outp[((long)(b_ * NH + h_) * DK + d_) * S_LEN + s_] = bf_round(v);
        }
      }
    }
  }
}

// ---------------- output-projection GEMM (fp32 out) ----------------
__global__ __launch_bounds__(256) void gemm_out(const unsigned short* __restrict__ A,
                                                const unsigned short* __restrict__ W,
                                                const float* __restrict__ bias,
                                                float* __restrict__ outp) {
  constexpr int K = DM, N = DM;
  __shared__ unsigned short lA[128 * 32];
  __shared__ unsigned short lB[128 * 32];
  const int tid = threadIdx.x;
  const int wave = tid >> 6, lane = tid & 63;
  const int wm = wave >> 1, wn = wave & 1;
  const int g = lane >> 4, c = lane & 15;
  const int bm = blockIdx.x, bn = blockIdx.y;

  const int srow = lane >> 2;
  const int scol = (lane & 3) * 8;

  f32x4 acc[4][4] = {};

  const unsigned short* Abase = A + (long)(bm * 128) * K;
  const unsigned short* Wbase = W + (long)(bn * 128) * K;

  for (int k0 = 0; k0 < K; k0 += 32) {
    __syncthreads();
#pragma unroll
    for (int i = 0; i < 2; ++i) {
      const int row = i * 64 + wave * 16;
      gload_lds16(Abase + (long)(row + srow) * K + k0 + scol, lA + row * 32);
      gload_lds16(Wbase + (long)(row + srow) * K + k0 + scol, lB + row * 32);
    }
    __syncthreads();

    short8 af[4], bf[4];
#pragma unroll
    for (int mi = 0; mi < 4; ++mi)
      af[mi] = *reinterpret_cast<const short8*>(&lA[(wm * 64 + mi * 16 + c) * 32 + g * 8]);
#pragma unroll
    for (int ni = 0; ni < 4; ++ni)
      bf[ni] = *reinterpret_cast<const short8*>(&lB[(wn * 64 + ni * 16 + c) * 32 + g * 8]);
#pragma unroll
    for (int mi = 0; mi < 4; ++mi)
#pragma unroll
      for (int ni = 0; ni < 4; ++ni)
        acc[mi][ni] =
            __builtin_amdgcn_mfma_f32_16x16x32_bf16(af[mi], bf[ni], acc[mi][ni], 0, 0, 0);
  }

#pragma unroll
  for (int mi = 0; mi < 4; ++mi) {
#pragma unroll
    for (int ni = 0; ni < 4; ++ni) {
      const int mg0 = bm * 128 + wm * 64 + mi * 16 + g * 4;
      const int ng = bn * 128 + wn * 64 + ni * 16 + c;
      const float bv = bias[ng];
#pragma unroll
      for (int r = 0; r < 4; ++r)
        outp[(long)(mg0 + r) * N + ng] = acc[mi][ni][r] + bv;
    }
  }
}

// ---------------- Flash attention: R13 structure + permlane32_swap PV-prep ----------------
// pf.w[0] = {a0.lo, a1.lo}, pf.w[2] = {a0.hi, a1.hi}: exactly v_permlane32_swap_b32(a0, a1)
// (swaps upper 32 lanes of op0 with lower 32 lanes of op1). Replaces 2 shfl_xor(32)
// + 4 v_cndmask per PV step with 2 pure-VALU permlanes (no LDS-port traffic).
__global__ __launch_bounds__(256) void attn_kernel(const unsigned short* __restrict__ Q,
                                                   const unsigned short* __restrict__ Kb,
                                                   const unsigned short* __restrict__ Vt,
                                                   unsigned short* __restrict__ ctx) {
  __shared__ unsigned short kbuf[2][2][64 * 64];  // [buf][sub][kv row][d], swizzled
  __shared__ unsigned short vbuf[2][2][64 * 64];  // [buf][sub][d row][kv], swizzled
  const int tid = threadIdx.x, wave = tid >> 6, lane = tid & 63;
  const int q = lane & 31;   // q column; also K/V LDS row selector
  const int h = lane >> 5;   // half-wave: owns k-slice h*8..h*8+7 of frags
  const int bid = blockIdx.x;
  const int swz = (bid & 7) * 128 + (bid >> 3);  // nwg=1024, 8 XCDs, bijective
  const int hd = swz >> 4, qb = swz & 15;
  const int q0 = qb * 128 + wave * 32;

  const unsigned short* Qh = Q + (long)hd * S_LEN * DK;
  const char* KhB = (const char*)(Kb + (long)hd * S_LEN * DK);
  const char* VhB = (const char*)(Vt + (long)hd * DK * S_LEN);

  const int srow_in = lane >> 3;                           // 0..7
  const int scolb = ((lane & 7) * 16) ^ (srow_in << 4);    // swizzled source byte col

  auto ldsrd = [&](const unsigned short* buf, int row, int colbyte) -> short8 {
    return *reinterpret_cast<const short8*>(
        reinterpret_cast<const char*>(buf) + row * 128 + (colbyte ^ ((row & 7) << 4)));
  };

  auto stage = [&](int b, int kv0) {
#pragma unroll
    for (int sub = 0; sub < 2; ++sub) {
#pragma unroll
      for (int r = 0; r < 2; ++r) {
        const int rowbase = (wave * 2 + r) * 8;          // wave-uniform
        const int row = rowbase + srow_in;
        gload_lds16((const unsigned short*)(KhB + (long)(kv0 + sub * 64 + row) * 128 + scolb),
                    &kbuf[b][sub][rowbase * 64]);
        gload_lds16((const unsigned short*)(VhB + (long)row * (S_LEN * 2) +
                                            (kv0 + sub * 64) * 2 + scolb),
                    &vbuf[b][sub][rowbase * 64]);
      }
    }
  };

  short8 qf[4];
#pragma unroll
  for (int d0 = 0; d0 < 4; ++d0)
    qf[d0] = *reinterpret_cast<const short8*>(&Qh[(long)(q0 + q) * DK + d0 * 16 + h * 8]);

  union { short s[8]; short8 v; } ones_u;
#pragma unroll
  for (int i = 0; i < 8; ++i) ones_u.s[i] = (short)0x3F80;
  const short8 ones8 = ones_u.v;

  f32x16 cacc0 = {}, cacc1 = {};  // ctx^T: d-blocks [0..31], [32..63] x 32 q
  f32x16 lacc = {};               // every reg = running sum_kv p̂[kv][q]
  float mrun = -1e30f;

  stage(0, 0);
  __syncthreads();

  int cur = 0;
  for (int t = 0; t < S_LEN / 128; ++t) {
    if (t + 1 < S_LEN / 128) stage(cur ^ 1, (t + 1) * 128);  // issue-early prefetch

#pragma unroll
    for (int p = 0; p < 2; ++p) {
      const unsigned short* kb = kbuf[cur][p];
      const unsigned short* vb = vbuf[cur][p];

      short8 kfA[4], kfB[4];
#pragma unroll
      for (int d0 = 0; d0 < 4; ++d0) {
        kfA[d0] = ldsrd(kb, q, d0 * 32 + h * 16);
        kfB[d0] = ldsrd(kb, 32 + q, d0 * 32 + h * 16);
      }
      __builtin_amdgcn_s_setprio(1);
      f32x16 stA = {}, stB = {};
#pragma unroll
      for (int d0 = 0; d0 < 4; ++d0) {
        stA = __builtin_amdgcn_mfma_f32_32x32x16_bf16(kfA[d0], qf[d0], stA, 0, 0, 0);
        stB = __builtin_amdgcn_mfma_f32_32x32x16_bf16(kfB[d0], qf[d0], stB, 0, 0, 0);
      }
      __builtin_amdgcn_s_setprio(0);

      // ---- max reduction via nested triples (v_max3) ----
      float m0 = fmaxf(fmaxf(stA[0], stA[1]), stA[2]);
      float m1 = fmaxf(fmaxf(stA[3], stA[4]), stA[5]);
      float m2 = fmaxf(fmaxf(stA[6], stA[7]), stA[8]);
      float m3 = fmaxf(fmaxf(stA[9], stA[10]), stA[11]);
      float m4 = fmaxf(fmaxf(stA[12], stA[13]), stA[14]);
      float m5 = fmaxf(fmaxf(stA[15], stB[0]), stB[1]);
      float m6 = fmaxf(fmaxf(stB[2], stB[3]), stB[4]);
      float m7 = fmaxf(fmaxf(stB[5], stB[6]), stB[7]);
      float m8 = fmaxf(fmaxf(stB[8], stB[9]), stB[10]);
      float m9 = fmaxf(fmaxf(stB[11], stB[12]), stB[13]);
      float n0 = fmaxf(fmaxf(m0, m1), m2);
      float n1 = fmaxf(fmaxf(m3, m4), m5);
      float n2 = fmaxf(fmaxf(m6, m7), m8);
      float n3 = fmaxf(fmaxf(m9, stB[14]), stB[15]);
      const float pml = fmaxf(fmaxf(n0, n1), fmaxf(n2, n3));

      if (__any(pml > mrun + 8.0f)) {  // rare; shfl only inside the branch
        const float pm = fmaxf(pml, __shfl_xor(pml, 32));
        const float mnew = fmaxf(mrun, pm);
        const float alpha = __builtin_amdgcn_exp2f(mrun - mnew);
        cacc0 *= alpha;
        cacc1 *= alpha;
        lacc *= alpha;
        mrun = mnew;  // stays pair-uniform: pm is pair-reduced
      }

#pragma unroll
      for (int r = 0; r < 16; ++r) {
        stA[r] = __builtin_amdgcn_exp2f(stA[r] - mrun);
        stB[r] = __builtin_amdgcn_exp2f(stB[r] - mrun);
      }

      unsigned pAA[4], pAB[4], pBA[4], pBB[4];
#pragma unroll
      for (int rq = 0; rq < 4; ++rq) {
        asm("v_cvt_pk_bf16_f32 %0, %1, %2" : "=v"(pAA[rq]) : "v"(stA[4 * rq]), "v"(stA[4 * rq + 1]));
        asm("v_cvt_pk_bf16_f32 %0, %1, %2" : "=v"(pAB[rq]) : "v"(stA[4 * rq + 2]), "v"(stA[4 * rq + 3]));
        asm("v_cvt_pk_bf16_f32 %0, %1, %2" : "=v"(pBA[rq]) : "v"(stB[4 * rq]), "v"(stB[4 * rq + 1]));
        asm("v_cvt_pk_bf16_f32 %0, %1, %2" : "=v"(pBB[rq]) : "v"(stB[4 * rq + 2]), "v"(stB[4 * rq + 3]));
      }

      short8 vf0[4], vf1[4];
#pragma unroll
      for (int s = 0; s < 4; ++s) {
        vf0[s] = ldsrd(vb, q, s * 32 + h * 16);
        vf1[s] = ldsrd(vb, 32 + q, s * 32 + h * 16);
      }
      __builtin_amdgcn_s_setprio(1);
#pragma unroll
      for (int s = 0; s < 4; ++s) {
        const unsigned a0 = (s < 2 ? pAA : pBA)[2 * (s & 1)];
        const unsigned a1 = (s < 2 ? pAA : pBA)[2 * (s & 1) + 1];
        const unsigned b0 = (s < 2 ? pAB : pBB)[2 * (s & 1)];
        const unsigned b1 = (s < 2 ? pAB : pBB)[2 * (s & 1) + 1];
        // pf.w[0]={a0.lo,a1.lo}, pf.w[2]={a0.hi,a1.hi}: exactly permlane32_swap(a0,a1)
        uint2v prA = __builtin_amdgcn_permlane32_swap(a0, a1, false, false);
        uint2v prB = __builtin_amdgcn_permlane32_swap(b0, b1, false, false);
        union { unsigned w[4]; short8 v; } pf;
        pf.w[0] = prA[0];
        pf.w[1] = prB[0];
        pf.w[2] = prA[1];
        pf.w[3] = prB[1];
        cacc0 = __builtin_amdgcn_mfma_f32_32x32x16_bf16(vf0[s], pf.v, cacc0, 0, 0, 0);
        cacc1 = __builtin_amdgcn_mfma_f32_32x32x16_bf16(vf1[s], pf.v, cacc1, 0, 0, 0);
        lacc = __builtin_amdgcn_mfma_f32_32x32x16_bf16(ones8, pf.v, lacc, 0, 0, 0);
      }
      __builtin_amdgcn_s_setprio(0);
    }

    __syncthreads();  // drains stage loads; protects both buffers
    cur ^= 1;
  }

  // ---- epilogue: l from ones-MFMA (all regs equal, both halves equal) ----
  const float inv = 1.0f / lacc[0];
  const int b_ = hd >> 4, h_ = hd & 15;
  const long row = ((long)b_ * S_LEN + q0 + q) * DM + h_ * DK;
#pragma unroll
  for (int rq = 0; rq < 4; ++rq) {
    ushort4 w0, w1;
    w0.x = bf_round(cacc0[4 * rq + 0] * inv);
    w0.y = bf_round(cacc0[4 * rq + 1] * inv);
    w0.z = bf_round(cacc0[4 * rq + 2] * inv);
    w0.w = bf_round(cacc0[4 * rq + 3] * inv);
    w1.x = bf_round(cacc1[4 * rq + 0] * inv);
    w1.y = bf_round(cacc1[4 * rq + 1] * inv);
    w1.z = bf_round(cacc1[4 * rq + 2] * inv);
    w1.w = bf_round(cacc1[4 * rq + 3] * inv);
    *reinterpret_cast<ushort4*>(&ctx[row + 8 * rq + 4 * h]) = w0;
    *reinterpret_cast<ushort4*>(&ctx[row + 32 + 8 * rq + 4 * h]) = w1;
  }
}

extern "C" void kernel_launch(void* const* d_in, const int* in_sizes, int n_in,
                              void* d_out, int out_size, void* d_ws, size_t ws_size,
                              hipStream_t stream) {
  const float* X  = (const float*)d_in[0];
  const float* Wq = (const float*)d_in[1];
  const float* bq = (const float*)d_in[2];
  const float* Wk = (const float*)d_in[3];
  const float* bk = (const float*)d_in[4];
  const float* Wv = (const float*)d_in[5];
  const float* bv = (const float*)d_in[6];
  const float* Wo = (const float*)d_in[7];
  const float* bo = (const float*)d_in[8];

  char* ws = (char*)d_ws;
  const long MB = 1l << 20;
  unsigned short* Xbf = (unsigned short*)(ws + 0 * MB);   // 16 MB
  unsigned short* Ctx = Xbf;                              // alias: X dead after V GEMM
  unsigned short* Wqb = (unsigned short*)(ws + 16 * MB);  // 2 MB each
  unsigned short* Wkb = (unsigned short*)(ws + 18 * MB);
  unsigned short* Wvb = (unsigned short*)(ws + 20 * MB);
  unsigned short* Wob = (unsigned short*)(ws + 22 * MB);
  unsigned short* Qb  = (unsigned short*)(ws + 24 * MB);  // 16 MB
  unsigned short* Kbf = (unsigned short*)(ws + 40 * MB);  // 16 MB
  unsigned short* Vtb = (unsigned short*)(ws + 56 * MB);  // 16 MB, ends at 72 MB

  CvtArgs ca;
  ca.in[0] = X;  ca.out[0] = Xbf;
  ca.in[1] = Wq; ca.out[1] = Wqb;
  ca.in[2] = Wk; ca.out[2] = Wkb;
  ca.in[3] = Wv; ca.out[3] = Wvb;
  ca.in[4] = Wo; ca.out[4] = Wob;
  cvt_all<<<4096 + 4 * 512, 256, 0, stream>>>(ca);

  QkvArgs qa;
  qa.W[0] = Wqb; qa.bias[0] = bq; qa.out[0] = Qb;
  qa.W[1] = Wkb; qa.bias[1] = bk; qa.out[1] = Kbf;
  qa.W[2] = Wvb; qa.bias[2] = bv; qa.out[2] = Vtb;
  gemm_qkv<<<dim3(M_TOT / 128, DM / 128, 3), 256, 0, stream>>>(Xbf, qa);

  attn_kernel<<<dim3(1024), 256, 0, stream>>>(Qb, Kbf, Vtb, Ctx);

  gemm_out<<<dim3(M_TOT / 128, DM / 128), 256, 0, stream>>>(Ctx, Wob, bo, (float*)d_out);
}